// Round 1
// baseline (275.277 us; speedup 1.0000x reference)
//
#include <hip/hip_runtime.h>
#include <hip/hip_bf16.h>

typedef float v4 __attribute__((ext_vector_type(4)));

#define N_NODES 10000
#define N_EDGES 160000

__device__ __forceinline__ float silu_f(float x) {
  return x / (1.0f + __expf(-x));
}

// ---------------- Kernel 1: node transform ----------------
// A[n][0:64]=s1, A[n][64+m*64+d]=v1[d][m]  (sender table, from W1_*)
// B likewise with W2_* (receiver table). Also writes mvec to out[n*4+1..3].
__global__ __launch_bounds__(256) void node_kernel(
    const float* __restrict__ nf,
    const float* __restrict__ W10, const float* __restrict__ W11,
    const float* __restrict__ W20, const float* __restrict__ W21,
    const float* __restrict__ Wm1,
    float* __restrict__ A, float* __restrict__ Bn, float* __restrict__ out)
{
  __shared__ float w10[4096], w11[4096], w20[4096], w21[4096];
  __shared__ float wm1s[64];
  __shared__ float feats[4][256];
  const int tid = threadIdx.x;
  for (int i = tid * 4; i < 4096; i += 1024) {
    *(v4*)&w10[i] = *(const v4*)&W10[i];
    *(v4*)&w11[i] = *(const v4*)&W11[i];
    *(v4*)&w20[i] = *(const v4*)&W20[i];
    *(v4*)&w21[i] = *(const v4*)&W21[i];
  }
  if (tid < 64) wm1s[tid] = Wm1[tid];
  const int nl = tid >> 6;   // node within 4-node group (one wave per node)
  const int d  = tid & 63;   // output channel
  for (int p = 0; p < 10; ++p) {
    const int n = blockIdx.x * 40 + p * 4 + nl;
    __syncthreads();
    *(v4*)&feats[nl][d * 4] = *(const v4*)&nf[n * 256 + d * 4];
    __syncthreads();
    float s1 = 0.f, s2 = 0.f;
    float v1x = 0.f, v1y = 0.f, v1z = 0.f, v2x = 0.f, v2y = 0.f, v2z = 0.f;
    #pragma unroll 8
    for (int c = 0; c < 64; ++c) {
      const float sc = feats[nl][c];
      const float vx = feats[nl][64 + c * 3 + 0];
      const float vy = feats[nl][64 + c * 3 + 1];
      const float vz = feats[nl][64 + c * 3 + 2];
      const float a10 = w10[c * 64 + d], a20 = w20[c * 64 + d];
      const float a11 = w11[c * 64 + d], a21 = w21[c * 64 + d];
      s1 += sc * a10;  s2 += sc * a20;
      v1x += vx * a11; v1y += vy * a11; v1z += vz * a11;
      v2x += vx * a21; v2y += vy * a21; v2z += vz * a21;
    }
    float* Ar = A  + (size_t)n * 256;
    float* Br = Bn + (size_t)n * 256;
    Ar[d] = s1 * 0.125f;
    Ar[64 + d]  = v1x * 0.125f;
    Ar[128 + d] = v1y * 0.125f;
    Ar[192 + d] = v1z * 0.125f;
    Br[d] = s2 * 0.125f;
    Br[64 + d]  = v2x * 0.125f;
    Br[128 + d] = v2y * 0.125f;
    Br[192 + d] = v2z * 0.125f;
    if (d < 3) {
      float mv = 0.f;
      #pragma unroll 8
      for (int c = 0; c < 64; ++c) mv += feats[nl][64 + c * 3 + d] * wm1s[c];
      out[n * 4 + 1 + d] = mv * 0.125f;
    }
  }
}

// fc layer (K=64): Hin[k][e] (LDS) x Wt[k][d] (LDS) -> silu -> Hout[d][e]
__device__ __forceinline__ void fc_layer64(const float* Hin, const float* Wt,
                                           float* Hout, int e0, int d0) {
  float acc[4][4];
  #pragma unroll
  for (int i = 0; i < 4; ++i)
    #pragma unroll
    for (int j = 0; j < 4; ++j) acc[i][j] = 0.f;
  #pragma unroll 8
  for (int k = 0; k < 64; ++k) {
    const v4 a = *(const v4*)&Hin[k * 64 + e0];
    const v4 b = *(const v4*)&Wt[k * 64 + d0];
    #pragma unroll
    for (int i = 0; i < 4; ++i)
      #pragma unroll
      for (int j = 0; j < 4; ++j) acc[i][j] += b[i] * a[j];
  }
  #pragma unroll
  for (int i = 0; i < 4; ++i) {
    v4 vv;
    #pragma unroll
    for (int j = 0; j < 4; ++j) {
      const float x = acc[i][j] * 0.125f;
      vv[j] = silu_f(x);
    }
    *(v4*)&Hout[(d0 + i) * 64 + e0] = vv;
  }
}

// ---------------- Kernel 2: fused edge pipeline ----------------
__global__ __launch_bounds__(256) void edge_kernel(
    const float* __restrict__ edge_attrs,
    const float* __restrict__ edge_feats,
    const int*   __restrict__ edge_index,
    const float* __restrict__ fcw0, const float* __restrict__ fcw1,
    const float* __restrict__ fcw2, const float* __restrict__ fcw3,
    const float* __restrict__ Wf,
    const float* __restrict__ A, const float* __restrict__ Bn,
    float* __restrict__ charges, float* __restrict__ p_out)
{
  __shared__ float H[2][4096];   // activations [unit k][edge e], ping-pong
  __shared__ float Wt[8192];     // per-layer weight tile [k][d]
  __shared__ float Psum[64];
  __shared__ int   sndL[64], rcvL[64];
  __shared__ float y0L[64], y1xL[64], y1yL[64], y1zL[64];

  const int tid = threadIdx.x;
  const int ebase = blockIdx.x * 64;

  if (tid < 64) {
    const int e = ebase + tid;
    sndL[tid] = edge_index[e];
    rcvL[tid] = edge_index[N_EDGES + e];
    const v4 ea = *(const v4*)&edge_attrs[e * 4];
    y0L[tid] = ea[0]; y1xL[tid] = ea[1]; y1yL[tid] = ea[2]; y1zL[tid] = ea[3];
    const v4 f0 = *(const v4*)&edge_feats[e * 8];
    const v4 f1 = *(const v4*)&edge_feats[e * 8 + 4];
    H[0][0 * 64 + tid] = f0[0]; H[0][1 * 64 + tid] = f0[1];
    H[0][2 * 64 + tid] = f0[2]; H[0][3 * 64 + tid] = f0[3];
    H[0][4 * 64 + tid] = f1[0]; H[0][5 * 64 + tid] = f1[1];
    H[0][6 * 64 + tid] = f1[2]; H[0][7 * 64 + tid] = f1[3];
    Psum[tid] = 0.f;
  }
  for (int i = tid; i < 512; i += 256) Wt[i] = fcw0[i];
  __syncthreads();

  const int e0 = (tid & 15) * 4;   // 4 edges per thread
  const int d0 = (tid >> 4) * 4;   // 4 output units per thread

  // ---- layer 1 (K=8, scale 1/sqrt(8)) ----
  {
    float acc[4][4];
    #pragma unroll
    for (int i = 0; i < 4; ++i)
      #pragma unroll
      for (int j = 0; j < 4; ++j) acc[i][j] = 0.f;
    #pragma unroll
    for (int k = 0; k < 8; ++k) {
      const v4 a = *(const v4*)&H[0][k * 64 + e0];
      const v4 b = *(const v4*)&Wt[k * 64 + d0];
      #pragma unroll
      for (int i = 0; i < 4; ++i)
        #pragma unroll
        for (int j = 0; j < 4; ++j) acc[i][j] += b[i] * a[j];
    }
    #pragma unroll
    for (int i = 0; i < 4; ++i) {
      v4 vv;
      #pragma unroll
      for (int j = 0; j < 4; ++j) {
        const float x = acc[i][j] * 0.35355339059327373f;
        vv[j] = silu_f(x);
      }
      *(v4*)&H[1][(d0 + i) * 64 + e0] = vv;
    }
  }
  __syncthreads();
  for (int i = tid * 4; i < 4096; i += 1024) *(v4*)&Wt[i] = *(const v4*)&fcw1[i];
  __syncthreads();
  fc_layer64(H[1], Wt, H[0], e0, d0);      // layer 2
  __syncthreads();
  for (int i = tid * 4; i < 4096; i += 1024) *(v4*)&Wt[i] = *(const v4*)&fcw2[i];
  __syncthreads();
  fc_layer64(H[0], Wt, H[1], e0, d0);      // layer 3
  __syncthreads();
  // stage fc_w3 columns 0:64 and 192:256 -> Wt[k][0:128]
  for (int i = tid; i < 8192; i += 256) {
    const int k = i >> 7, j = i & 127;
    Wt[i] = fcw3[k * 256 + (j < 64 ? j : 128 + j)];
  }
  __syncthreads();

  // ---- layer 4 (no silu), keep in registers ----
  float accA[4][4], accB[4][4];
  #pragma unroll
  for (int i = 0; i < 4; ++i)
    #pragma unroll
    for (int j = 0; j < 4; ++j) { accA[i][j] = 0.f; accB[i][j] = 0.f; }
  #pragma unroll 8
  for (int k = 0; k < 64; ++k) {
    const v4 a  = *(const v4*)&H[1][k * 64 + e0];
    const v4 bA = *(const v4*)&Wt[k * 128 + d0];
    const v4 bB = *(const v4*)&Wt[k * 128 + 64 + d0];
    #pragma unroll
    for (int i = 0; i < 4; ++i)
      #pragma unroll
      for (int j = 0; j < 4; ++j) {
        accA[i][j] += bA[i] * a[j];
        accB[i][j] += bB[i] * a[j];
      }
  }

  // ---- fused gather + contraction ----
  const v4 wfA = *(const v4*)&Wf[d0];
  const v4 wfB = *(const v4*)&Wf[64 + d0];
  #pragma unroll
  for (int j = 0; j < 4; ++j) {
    const int el = e0 + j;
    const int snd = sndL[el], rcv = rcvL[el];
    const float* Ar = A  + (size_t)snd * 256;
    const float* Br = Bn + (size_t)rcv * 256;
    const v4 As = *(const v4*)&Ar[d0];
    const v4 Bs = *(const v4*)&Br[d0];
    const v4 Ax = *(const v4*)&Ar[64 + d0];
    const v4 Ay = *(const v4*)&Ar[128 + d0];
    const v4 Az = *(const v4*)&Ar[192 + d0];
    const v4 Bx = *(const v4*)&Br[64 + d0];
    const v4 By = *(const v4*)&Br[128 + d0];
    const v4 Bz = *(const v4*)&Br[192 + d0];
    const float y0 = y0L[el], yx = y1xL[el], yy = y1yL[el], yz = y1zL[el];
    float part = 0.f;
    #pragma unroll
    for (int i = 0; i < 4; ++i) {
      const float w0c = accA[i][j] * 0.125f;
      const float w3c = accB[i][j] * 0.125f;
      const float bs  = As[i] + Bs[i];
      const float bvd = (Ax[i] + Bx[i]) * yx + (Ay[i] + By[i]) * yy + (Az[i] + Bz[i]) * yz;
      part += w0c * bs * y0 * wfA[i] + w3c * bvd * 0.5773502691896258f * wfB[i];
    }
    atomicAdd(&Psum[el], part);
  }
  __syncthreads();
  if (tid < 64) {
    const int e = ebase + tid;
    const float p = Psum[tid] * 0.0022097086912079608f;  // 1/sqrt(128)/40
    p_out[e] = p;
    atomicAdd(&charges[rcvL[tid]], p);
    atomicAdd(&charges[sndL[tid]], -p);
  }
}

// ---------------- Kernel 3: finalize ----------------
__global__ void finalize_kernel(const float* __restrict__ charges, float* __restrict__ out) {
  const int n = blockIdx.x * 256 + threadIdx.x;
  if (n < N_NODES) out[n * 4] = charges[n];
}

extern "C" void kernel_launch(void* const* d_in, const int* in_sizes, int n_in,
                              void* d_out, int out_size, void* d_ws, size_t ws_size,
                              hipStream_t stream) {
  const float* node_feats = (const float*)d_in[1];
  const float* edge_attrs = (const float*)d_in[2];
  const float* edge_feats = (const float*)d_in[3];
  const int*   edge_index = (const int*)d_in[4];
  const float* W10  = (const float*)d_in[8];
  const float* W11  = (const float*)d_in[9];
  const float* W20  = (const float*)d_in[10];
  const float* W21  = (const float*)d_in[11];
  const float* fcw0 = (const float*)d_in[12];
  const float* fcw1 = (const float*)d_in[13];
  const float* fcw2 = (const float*)d_in[14];
  const float* fcw3 = (const float*)d_in[15];
  const float* Wf   = (const float*)d_in[16];
  const float* Wm1  = (const float*)d_in[17];
  float* out = (float*)d_out;

  char* ws = (char*)d_ws;
  float* A       = (float*)ws;                                    // N*256 f32
  float* Bn      = (float*)(ws + (size_t)N_NODES * 256 * 4);      // N*256 f32
  float* charges = (float*)(ws + (size_t)N_NODES * 256 * 4 * 2);  // N f32

  hipMemsetAsync(charges, 0, N_NODES * sizeof(float), stream);
  node_kernel<<<250, 256, 0, stream>>>(node_feats, W10, W11, W20, W21, Wm1, A, Bn, out);
  edge_kernel<<<2500, 256, 0, stream>>>(edge_attrs, edge_feats, edge_index,
      fcw0, fcw1, fcw2, fcw3, Wf, A, Bn, charges, out + 40000);
  finalize_kernel<<<40, 256, 0, stream>>>(charges, out);
}

// Round 2
// 183.249 us; speedup vs baseline: 1.5022x; 1.5022x over previous
//
#include <hip/hip_runtime.h>
#include <hip/hip_bf16.h>

typedef float v4f __attribute__((ext_vector_type(4)));
typedef float f32x4 __attribute__((ext_vector_type(4)));
typedef unsigned short u16;
typedef unsigned short us4 __attribute__((ext_vector_type(4)));
typedef unsigned short us8 __attribute__((ext_vector_type(8)));
typedef short s16x8 __attribute__((ext_vector_type(8)));

#define N_NODES 10000
#define N_EDGES 160000

// XOR-swizzle on ushort index (bytes bits 4-6 <=> ushort-idx bits 3-5): keeps
// 16B slots intact, spreads stride-128B rows across bank quads (T2).
#define SWZ(idx, row) ((idx) ^ (((row) & 7) << 3))

__device__ __forceinline__ u16 f2b(float x) {
  union { float f; unsigned u; } v; v.f = x;
  unsigned r = v.u + 0x7fffu + ((v.u >> 16) & 1u);
  return (u16)(r >> 16);
}
__device__ __forceinline__ float b2f(u16 u) {
  union { unsigned u; float f; } v; v.u = ((unsigned)u) << 16; return v.f;
}
__device__ __forceinline__ float silu_f(float x) { return x / (1.0f + __expf(-x)); }

// ---------------- prep: pack weight A-fragments (lane-major, bf16) ----------
// A[unit][k] fragments for C[unit][edge|node] MFMAs.
// frag f: lane holds A[ut*16 + (lane&15)][kw*32 + (lane>>4)*8 + j], j=0..7.
// Sections (in 8-ushort frags): L2 @0 (512), L3 @512, L4 @1024 (1024),
// NS @2048 (1024), NV @3072 (1024).
__global__ __launch_bounds__(256) void prep_kernel(
    const float* __restrict__ fcw1, const float* __restrict__ fcw2,
    const float* __restrict__ fcw3,
    const float* __restrict__ W10, const float* __restrict__ W20,
    const float* __restrict__ W11, const float* __restrict__ W21,
    u16* __restrict__ prep)
{
  const int fid = blockIdx.x * 256 + threadIdx.x;   // 0..4095
  int f, sec;
  if (fid < 512)       { sec = 0; f = fid; }
  else if (fid < 1024) { sec = 1; f = fid - 512; }
  else if (fid < 2048) { sec = 2; f = fid - 1024; }
  else if (fid < 3072) { sec = 3; f = fid - 2048; }
  else                 { sec = 4; f = fid - 3072; }
  const int lane = f & 63, kw = (f >> 6) & 1, ut = f >> 7;
  us8 vals;
  #pragma unroll
  for (int j = 0; j < 8; ++j) {
    const int k = kw * 32 + (lane >> 4) * 8 + j;
    float v;
    if (sec == 0) v = fcw1[k * 64 + ut * 16 + (lane & 15)];
    else if (sec == 1) v = fcw2[k * 64 + ut * 16 + (lane & 15)];
    else if (sec == 2) {
      const int col = (ut < 4) ? (ut * 16 + (lane & 15)) : (192 + (ut - 4) * 16 + (lane & 15));
      v = fcw3[k * 256 + col];
    } else if (sec == 3) {
      const int u = ut * 16 + (lane & 15);
      v = (u < 64) ? W10[k * 64 + u] : W20[k * 64 + (u - 64)];
    } else {
      const int u = ut * 16 + (lane & 15);
      v = (u < 64) ? W11[k * 64 + u] : W21[k * 64 + (u - 64)];
    }
    vals[j] = f2b(v);
  }
  *(us8*)&prep[(size_t)fid * 8] = vals;
}

// ---------------- node kernel: MFMA node transforms -> bf16 tables ----------
// Atab[n][256] = [s1 | v1x | v1y | v1z], Btab likewise (s2, v2), bf16, /8 folded.
__global__ __launch_bounds__(256) void node_kernel(
    const float* __restrict__ nf,
    const u16* __restrict__ prepNS, const u16* __restrict__ prepNV,
    const float* __restrict__ Wm1,
    u16* __restrict__ Atab, u16* __restrict__ Btab, float* __restrict__ out)
{
  __shared__ u16 Ss[4096];       // [node][c] swizzled
  __shared__ u16 Vs[3 * 4096];   // [m][node][c] swizzled
  const int tid = threadIdx.x;
  const int w = tid >> 6, lane = tid & 63;
  const int nb = blockIdx.x;

  // stage + f32->bf16 convert + de-interleave v
  #pragma unroll
  for (int it = 0; it < 16; ++it) {
    const int flat = it * 1024 + tid * 4;
    const int nl = flat >> 8, col = flat & 255;
    const int node = nb * 64 + nl;
    v4f x = {0.f, 0.f, 0.f, 0.f};
    if (node < N_NODES) x = *(const v4f*)&nf[(size_t)node * 256 + col];
    #pragma unroll
    for (int i = 0; i < 4; ++i) {
      const int c2 = col + i;
      const u16 b = f2b(x[i]);
      if (c2 < 64) {
        Ss[SWZ(nl * 64 + c2, nl)] = b;
      } else {
        const int cc = c2 - 64;
        const int c = cc / 3, m = cc - c * 3;
        Vs[m * 4096 + SWZ(nl * 64 + c, nl)] = b;
      }
    }
  }
  __syncthreads();

  const int nr = lane & 15, kg = (lane >> 4) * 8;
  #pragma unroll
  for (int pass = 0; pass < 4; ++pass) {
    const u16* plane = (pass == 0) ? Ss : &Vs[(pass - 1) * 4096];
    const u16* pw = (pass == 0) ? prepNS : prepNV;
    #pragma unroll
    for (int half = 0; half < 2; ++half) {
      const int utg = w * 2 + half;
      const s16x8 a0 = *(const s16x8*)&pw[((utg * 2 + 0) * 64 + lane) * 8];
      const s16x8 a1 = *(const s16x8*)&pw[((utg * 2 + 1) * 64 + lane) * 8];
      #pragma unroll
      for (int nt = 0; nt < 4; ++nt) {
        const int nloc = nt * 16 + nr;
        const s16x8 b0 = *(const s16x8*)&plane[SWZ(nloc * 64 + kg, nloc)];
        const s16x8 b1 = *(const s16x8*)&plane[SWZ(nloc * 64 + 32 + kg, nloc)];
        f32x4 acc = {0.f, 0.f, 0.f, 0.f};
        acc = __builtin_amdgcn_mfma_f32_16x16x32_bf16(a0, b0, acc, 0, 0, 0);
        acc = __builtin_amdgcn_mfma_f32_16x16x32_bf16(a1, b1, acc, 0, 0, 0);
        const int node = nb * 64 + nloc;
        if (node < N_NODES) {
          us4 st;
          #pragma unroll
          for (int j = 0; j < 4; ++j) st[j] = f2b(acc[j] * 0.125f);
          u16* tab = (utg < 4) ? Atab : Btab;
          const int ch = pass * 64 + ((utg * 16) & 63) + (lane >> 4) * 4;
          *(us4*)&tab[(size_t)node * 256 + ch] = st;
        }
      }
    }
  }

  // mvec (uses Vs, unchanged since staging barrier)
  if (tid < 192) {
    const int nl3 = tid / 3, m = tid - nl3 * 3;
    const int node = nb * 64 + nl3;
    if (node < N_NODES) {
      float acc = 0.f;
      #pragma unroll 8
      for (int c = 0; c < 64; ++c)
        acc += b2f(Vs[m * 4096 + SWZ(nl3 * 64 + c, nl3)]) * Wm1[c];
      out[node * 4 + 1 + m] = acc * 0.125f;
    }
  }
}

// layer L2/L3: Hin -> Hout (both swizzled [edge][k] bf16), weights from prep
__device__ __forceinline__ void mfma_layer(const u16* Hin, u16* Hout,
                                           const u16* __restrict__ prepW,
                                           int w, int lane) {
  const s16x8 a0 = *(const s16x8*)&prepW[((w * 2 + 0) * 64 + lane) * 8];
  const s16x8 a1 = *(const s16x8*)&prepW[((w * 2 + 1) * 64 + lane) * 8];
  const int er = lane & 15, kg = (lane >> 4) * 8;
  #pragma unroll
  for (int et = 0; et < 4; ++et) {
    const int e = et * 16 + er;
    const s16x8 b0 = *(const s16x8*)&Hin[SWZ(e * 64 + kg, e)];
    const s16x8 b1 = *(const s16x8*)&Hin[SWZ(e * 64 + 32 + kg, e)];
    f32x4 acc = {0.f, 0.f, 0.f, 0.f};
    acc = __builtin_amdgcn_mfma_f32_16x16x32_bf16(a0, b0, acc, 0, 0, 0);
    acc = __builtin_amdgcn_mfma_f32_16x16x32_bf16(a1, b1, acc, 0, 0, 0);
    us4 st;
    #pragma unroll
    for (int j = 0; j < 4; ++j) st[j] = f2b(silu_f(acc[j] * 0.125f));
    *(us4*)&Hout[SWZ(e * 64 + w * 16 + (lane >> 4) * 4, e)] = st;
  }
}

// ---------------- edge kernel: MLP (MFMA) + gather + contraction ------------
__global__ __launch_bounds__(256) void edge_kernel(
    const float* __restrict__ edge_attrs,
    const float* __restrict__ edge_feats,
    const int*   __restrict__ edge_index,
    const float* __restrict__ fcw0,
    const u16*   __restrict__ prep,     // L2 @0, L3 @512*8, L4 @1024*8
    const float* __restrict__ Wf,
    const u16*   __restrict__ Atab, const u16* __restrict__ Btab,
    float* __restrict__ charges, float* __restrict__ p_out)
{
  __shared__ float F[512];       // [k][e] f32 edge feats
  __shared__ float W0L[512];     // fc_w0
  __shared__ u16 HA[4096], HB[4096];
  __shared__ int sndL[64], rcvL[64];
  __shared__ float y0L[64], yxL[64], yyL[64], yzL[64];
  __shared__ float Psum[64];

  const int tid = threadIdx.x;
  const int w = tid >> 6, lane = tid & 63;
  const int ebase = blockIdx.x * 64;

  if (tid < 64) {
    const int e = ebase + tid;
    sndL[tid] = edge_index[e];
    rcvL[tid] = edge_index[N_EDGES + e];
    const v4f ea = *(const v4f*)&edge_attrs[(size_t)e * 4];
    y0L[tid] = ea[0]; yxL[tid] = ea[1]; yyL[tid] = ea[2]; yzL[tid] = ea[3];
    const v4f f0 = *(const v4f*)&edge_feats[(size_t)e * 8];
    const v4f f1 = *(const v4f*)&edge_feats[(size_t)e * 8 + 4];
    #pragma unroll
    for (int k = 0; k < 4; ++k) { F[k * 64 + tid] = f0[k]; F[(k + 4) * 64 + tid] = f1[k]; }
    Psum[tid] = 0.f;
  }
  for (int i = tid; i < 512; i += 256) W0L[i] = fcw0[i];
  __syncthreads();

  // ---- layer 1 (VALU, K=8): each wave: all 64 edges x units w*16..w*16+15
  {
    const int e = lane;
    float acc[16];
    #pragma unroll
    for (int j = 0; j < 16; ++j) acc[j] = 0.f;
    #pragma unroll
    for (int k = 0; k < 8; ++k) {
      const float fv = F[k * 64 + e];
      #pragma unroll
      for (int q = 0; q < 4; ++q) {
        const v4f wr = *(const v4f*)&W0L[k * 64 + w * 16 + q * 4];
        #pragma unroll
        for (int j = 0; j < 4; ++j) acc[q * 4 + j] += fv * wr[j];
      }
    }
    us8 o0, o1;
    #pragma unroll
    for (int j = 0; j < 8; ++j) {
      o0[j] = f2b(silu_f(acc[j] * 0.35355339059327373f));
      o1[j] = f2b(silu_f(acc[8 + j] * 0.35355339059327373f));
    }
    *(us8*)&HA[SWZ(e * 64 + w * 16, e)] = o0;
    *(us8*)&HA[SWZ(e * 64 + w * 16 + 8, e)] = o1;
  }
  __syncthreads();
  mfma_layer(HA, HB, prep, w, lane);                 // layer 2
  __syncthreads();
  mfma_layer(HB, HA, prep + 512 * 8, w, lane);       // layer 3
  __syncthreads();

  // ---- layer 4 (MFMA) + gather + contraction
  const u16* prepL4 = prep + 1024 * 8;
  const s16x8 as0 = *(const s16x8*)&prepL4[((w * 2 + 0) * 64 + lane) * 8];
  const s16x8 as1 = *(const s16x8*)&prepL4[((w * 2 + 1) * 64 + lane) * 8];
  const s16x8 av0 = *(const s16x8*)&prepL4[(((4 + w) * 2 + 0) * 64 + lane) * 8];
  const s16x8 av1 = *(const s16x8*)&prepL4[(((4 + w) * 2 + 1) * 64 + lane) * 8];
  const int er = lane & 15, kg = (lane >> 4) * 8;
  const int cb = w * 16 + (lane >> 4) * 4;           // channel base (4 ch)
  const v4f wfA = *(const v4f*)&Wf[cb];
  v4f wfB = *(const v4f*)&Wf[64 + cb];
  #pragma unroll
  for (int j = 0; j < 4; ++j) wfB[j] *= 0.5773502691896258f;

  #pragma unroll
  for (int et = 0; et < 4; ++et) {
    const int e = et * 16 + er;
    const s16x8 b0 = *(const s16x8*)&HA[SWZ(e * 64 + kg, e)];
    const s16x8 b1 = *(const s16x8*)&HA[SWZ(e * 64 + 32 + kg, e)];
    f32x4 accS = {0.f, 0.f, 0.f, 0.f}, accV = {0.f, 0.f, 0.f, 0.f};
    accS = __builtin_amdgcn_mfma_f32_16x16x32_bf16(as0, b0, accS, 0, 0, 0);
    accS = __builtin_amdgcn_mfma_f32_16x16x32_bf16(as1, b1, accS, 0, 0, 0);
    accV = __builtin_amdgcn_mfma_f32_16x16x32_bf16(av0, b0, accV, 0, 0, 0);
    accV = __builtin_amdgcn_mfma_f32_16x16x32_bf16(av1, b1, accV, 0, 0, 0);

    const int snd = sndL[e], rcv = rcvL[e];
    const u16* ra = Atab + (size_t)snd * 256;
    const u16* rb = Btab + (size_t)rcv * 256;
    const us4 As = *(const us4*)&ra[cb];
    const us4 Ax = *(const us4*)&ra[64 + cb];
    const us4 Ay = *(const us4*)&ra[128 + cb];
    const us4 Az = *(const us4*)&ra[192 + cb];
    const us4 Bs = *(const us4*)&rb[cb];
    const us4 Bx = *(const us4*)&rb[64 + cb];
    const us4 By = *(const us4*)&rb[128 + cb];
    const us4 Bz = *(const us4*)&rb[192 + cb];
    const float y0 = y0L[e], yx = yxL[e], yy = yyL[e], yz = yzL[e];
    float part = 0.f;
    #pragma unroll
    for (int j = 0; j < 4; ++j) {
      const float bs = b2f(As[j]) + b2f(Bs[j]);
      const float bv = (b2f(Ax[j]) + b2f(Bx[j])) * yx +
                       (b2f(Ay[j]) + b2f(By[j])) * yy +
                       (b2f(Az[j]) + b2f(Bz[j])) * yz;
      part += accS[j] * bs * y0 * wfA[j] + accV[j] * bv * wfB[j];
    }
    part += __shfl_xor(part, 16);
    part += __shfl_xor(part, 32);
    if (lane < 16) atomicAdd(&Psum[e], part);
  }
  __syncthreads();
  if (tid < 64) {
    // fold: 0.125 (layer-4 1/sqrt(64)) / sqrt(128) / 40
    const float p = Psum[tid] * 2.7621358640766505e-4f;
    p_out[ebase + tid] = p;
    atomicAdd(&charges[rcvL[tid]], p);
    atomicAdd(&charges[sndL[tid]], -p);
  }
}

// ---------------- finalize ----------------
__global__ void finalize_kernel(const float* __restrict__ charges, float* __restrict__ out) {
  const int n = blockIdx.x * 256 + threadIdx.x;
  if (n < N_NODES) out[n * 4] = charges[n];
}

extern "C" void kernel_launch(void* const* d_in, const int* in_sizes, int n_in,
                              void* d_out, int out_size, void* d_ws, size_t ws_size,
                              hipStream_t stream) {
  const float* node_feats = (const float*)d_in[1];
  const float* edge_attrs = (const float*)d_in[2];
  const float* edge_feats = (const float*)d_in[3];
  const int*   edge_index = (const int*)d_in[4];
  const float* W10  = (const float*)d_in[8];
  const float* W11  = (const float*)d_in[9];
  const float* W20  = (const float*)d_in[10];
  const float* W21  = (const float*)d_in[11];
  const float* fcw0 = (const float*)d_in[12];
  const float* fcw1 = (const float*)d_in[13];
  const float* fcw2 = (const float*)d_in[14];
  const float* fcw3 = (const float*)d_in[15];
  const float* Wf   = (const float*)d_in[16];
  const float* Wm1  = (const float*)d_in[17];
  float* out = (float*)d_out;

  char* ws = (char*)d_ws;
  u16*   Atab    = (u16*)ws;                              // 10000*256 u16 = 5.12MB
  u16*   Btab    = (u16*)(ws + 5120000);
  float* charges = (float*)(ws + 10240000);               // 40KB
  u16*   prep    = (u16*)(ws + 10280000);                 // 4096 frags * 16B

  prep_kernel<<<16, 256, 0, stream>>>(fcw1, fcw2, fcw3, W10, W20, W11, W21, prep);
  hipMemsetAsync(charges, 0, N_NODES * sizeof(float), stream);
  node_kernel<<<157, 256, 0, stream>>>(node_feats, prep + 2048 * 8, prep + 3072 * 8,
                                       Wm1, Atab, Btab, out);
  edge_kernel<<<2500, 256, 0, stream>>>(edge_attrs, edge_feats, edge_index,
                                        fcw0, prep, Wf, Atab, Btab,
                                        charges, out + 40000);
  finalize_kernel<<<40, 256, 0, stream>>>(charges, out);
}